// Round 13
// baseline (97.995 us; speedup 1.0000x reference)
//
#include <hip/hip_runtime.h>
#include <hip/hip_bf16.h>

#define DIM 256
#define NAGENT 64
#define NBATCH 256

typedef __bf16 bf16_t;
typedef bf16_t bf16x4 __attribute__((ext_vector_type(4)));
typedef bf16_t bf16x8 __attribute__((ext_vector_type(8)));
typedef float f32x4 __attribute__((ext_vector_type(4)));

// Single kernel, 256 blocks x 1024 threads (16 waves -> 1 block/CU, all
// co-resident; publish-before-spin => deadlock-free).
// Block b:
//   A) issue h[b] loads (4 rows x 4 cols per thread, held in regs)
//   B) prep row b at the R4-proven 16-wave config:
//      t1 = Wh[b]@Ws ; Wc[b] = bf16(t1@Wa) ; bc[b]
//      publish: release fence + atomicAdd; 256th publisher sets 8 replicated
//      flag words (256B apart) -- pollers spread over 8 lines, no congestion
//   C) column sums + g build (bf16, XOR-swizzled LDS)
//   D) poll flag[b&7] with s_sleep backoff; one threadfence after exit
//   E) 16-wave MFMA GEMM: out[b] = relu(g @ Wc^T + bc)
__global__ __launch_bounds__(1024) void mac_one_kernel(
    const float* __restrict__ h,
    const float* __restrict__ Wh, const float* __restrict__ Ws,
    const float* __restrict__ Wa, const float* __restrict__ ba,
    const float* __restrict__ bs, const float* __restrict__ bh,
    bf16_t* __restrict__ Wc, float* __restrict__ bcw,
    unsigned int* syncw, float* __restrict__ out) {
  const int b = blockIdx.x;
  const int t = threadIdx.x;
  const int cg = t & 63;   // column group: cols cg*4..+3 (prep: jg)
  const int rg = t >> 6;   // wave id 0..15 (h rows rg*4..+3; prep k-chunk)

  __shared__ __align__(16) bf16_t g[NAGENT * DIM];  // 32 KB
  __shared__ f32x4 part[16][64];                    // 16 KB prep partials
  __shared__ f32x4 ps[16][64];                      // 16 KB h col-sum partials
  __shared__ float whl[DIM];                        // 1 KB
  __shared__ float t1l[DIM];                        // 1 KB

  const float* hb = h + (size_t)b * NAGENT * DIM;

  // ---- A: issue h loads (held in registers through prep) ----
  f32x4 v[4];
#pragma unroll
  for (int i = 0; i < 4; ++i)
    v[i] = *(const f32x4*)&hb[(rg * 4 + i) * DIM + cg * 4];

  if (t < 64) *(f32x4*)&whl[t * 4] = *(const f32x4*)&Wh[b * DIM + t * 4];
  __syncthreads();

  // ---- B stage 1: t1 = Wh[b] @ Ws (k-chunk rg: 16 k's, cols cg*4..+3) ----
  {
    f32x4 a = {0.f, 0.f, 0.f, 0.f};
#pragma unroll
    for (int ki = 0; ki < 16; ++ki) {
      const int k = rg * 16 + ki;
      a += whl[k] * *(const f32x4*)&Ws[k * DIM + cg * 4];
    }
    part[rg][cg] = a;
  }
  __syncthreads();
  if (t < 64) {
    f32x4 s = part[0][t];
#pragma unroll
    for (int r = 1; r < 16; ++r) s += part[r][t];
    *(f32x4*)&t1l[t * 4] = s;
  }
  __syncthreads();

  // ---- B stage 2: Wc row = t1 @ Wa ----
  {
    f32x4 a = {0.f, 0.f, 0.f, 0.f};
#pragma unroll
    for (int ki = 0; ki < 16; ++ki) {
      const int k = rg * 16 + ki;
      a += t1l[k] * *(const f32x4*)&Wa[k * DIM + cg * 4];
    }
    part[rg][cg] = a;
  }
  __syncthreads();

  // ---- B finalize + publish (wave 0 only; its fence covers its own stores) ----
  if (t < 64) {
    f32x4 s = part[0][t];
#pragma unroll
    for (int r = 1; r < 16; ++r) s += part[r][t];
    bf16x4 wb;
    wb[0] = (bf16_t)s[0]; wb[1] = (bf16_t)s[1];
    wb[2] = (bf16_t)s[2]; wb[3] = (bf16_t)s[3];
    *(bf16x4*)&Wc[b * DIM + t * 4] = wb;
    // bc[b] = dot(t1,ba) + dot(Wh[b],bs) + bh[b]
    const f32x4 t14 = *(const f32x4*)&t1l[t * 4];
    const f32x4 ba4 = *(const f32x4*)&ba[t * 4];
    const f32x4 wh4 = *(const f32x4*)&whl[t * 4];
    const f32x4 bs4 = *(const f32x4*)&bs[t * 4];
    const f32x4 pp = t14 * ba4 + wh4 * bs4;
    float p = pp[0] + pp[1] + pp[2] + pp[3];
#pragma unroll
    for (int s2 = 32; s2 > 0; s2 >>= 1) p += __shfl_down(p, s2, 64);
    if (t == 0) {
      bcw[b] = p + bh[b];
      __threadfence();  // release: this wave's Wc row + bcw visible device-wide
      const unsigned int old = atomicAdd(syncw, 1u);
      if (old == NBATCH - 1) {
        // last publisher: set 8 replicated flags, 256B apart
#pragma unroll
        for (int f = 0; f < 8; ++f)
          __hip_atomic_store(&syncw[64 + f * 64], 1u, __ATOMIC_RELEASE,
                             __HIP_MEMORY_SCOPE_AGENT);
      }
    }
  }

  // ---- C: column sums + g build ----
  f32x4 s4 = v[0];
#pragma unroll
  for (int i = 1; i < 4; ++i) s4 += v[i];
  ps[rg][cg] = s4;
  __syncthreads();
  f32x4 hs = ps[0][cg];
#pragma unroll
  for (int r = 1; r < 16; ++r) hs += ps[r][cg];

  const float inv = 1.0f / 63.0f;
#pragma unroll
  for (int i = 0; i < 4; ++i) {
    const int row = rg * 4 + i;
    const f32x4 gv = (hs - v[i]) * inv;
    bf16x4 gb;
    gb[0] = (bf16_t)gv[0]; gb[1] = (bf16_t)gv[1];
    gb[2] = (bf16_t)gv[2]; gb[3] = (bf16_t)gv[3];
    *(bf16x4*)&g[row * DIM + ((cg * 4) ^ ((row & 7) << 3))] = gb;
  }
  __syncthreads();

  // ---- D: poll the XCD-replicated flag (low-rate, 8 lines, backoff) ----
  if (t == 0) {
    while (__hip_atomic_load(&syncw[64 + (b & 7) * 64], __ATOMIC_RELAXED,
                             __HIP_MEMORY_SCOPE_AGENT) == 0u)
      __builtin_amdgcn_s_sleep(16);
  }
  __syncthreads();
  __threadfence();  // acquire: safe to read all Wc rows + bcw

  // ---- E: GEMM. 16 waves: wave rg -> cols rg*16..+15, rows 0..63 ----
  const int lane = t & 63, lrow = lane & 15, lgrp = lane >> 4;

  f32x4 acc[4];
#pragma unroll
  for (int rt = 0; rt < 4; ++rt) acc[rt] = (f32x4){0.f, 0.f, 0.f, 0.f};

#pragma unroll
  for (int kk = 0; kk < 8; ++kk) {
    const int k0 = kk * 32 + lgrp * 8;
    const bf16x8 bfrag = *(const bf16x8*)&Wc[(rg * 16 + lrow) * DIM + k0];
#pragma unroll
    for (int rt = 0; rt < 4; ++rt) {
      const int arow = rt * 16 + lrow;
      const bf16x8 afrag =
          *(const bf16x8*)&g[arow * DIM + (k0 ^ ((arow & 7) << 3))];
      acc[rt] = __builtin_amdgcn_mfma_f32_16x16x32_bf16(afrag, bfrag, acc[rt], 0, 0, 0);
    }
  }

  // epilogue: C/D layout col=lane&15, row=(lane>>4)*4+reg  [m89-verified]
  const int col = rg * 16 + lrow;
  const float bcv = bcw[col];
  float* ob = out + (size_t)b * NAGENT * DIM;
#pragma unroll
  for (int rt = 0; rt < 4; ++rt) {
#pragma unroll
    for (int r = 0; r < 4; ++r) {
      const int row = rt * 16 + lgrp * 4 + r;
      const float val = acc[rt][r] + bcv;
      ob[row * DIM + col] = val > 0.f ? val : 0.f;
    }
  }
}

extern "C" void kernel_launch(void* const* d_in, const int* in_sizes, int n_in,
                              void* d_out, int out_size, void* d_ws, size_t ws_size,
                              hipStream_t stream) {
  const float* h  = (const float*)d_in[0];  // hidden_state (16384,256)
  const float* Wa = (const float*)d_in[1];  // W_act (256,256)
  const float* ba = (const float*)d_in[2];  // b_act (256,)
  const float* Ws = (const float*)d_in[3];  // W_sum (256,256)
  const float* bs = (const float*)d_in[4];  // b_sum (256,)
  const float* Wh = (const float*)d_in[5];  // W_head (256,256)
  const float* bh = (const float*)d_in[6];  // b_head (256,)
  float* out = (float*)d_out;

  char* ws = (char*)d_ws;
  bf16_t* Wc  = (bf16_t*)ws;                        // 128 KB
  float*  bcw = (float*)(ws + 128 * 1024);          // 1 KB
  unsigned int* syncw = (unsigned int*)(ws + 132 * 1024);  // counter + 8 flags

  // deterministic per-call reset of counter + flags (graph-capturable)
  hipMemsetAsync(syncw, 0, 4096, stream);

  mac_one_kernel<<<NBATCH, 1024, 0, stream>>>(h, Wh, Ws, Wa, ba, bs, bh,
                                              Wc, bcw, syncw, out);
}

// Round 14
// 33.684 us; speedup vs baseline: 2.9093x; 2.9093x over previous
//
#include <hip/hip_runtime.h>
#include <hip/hip_bf16.h>

#define DIM 256
#define NAGENT 64
#define NBATCH 256

typedef __bf16 bf16_t;
typedef bf16_t bf16x4 __attribute__((ext_vector_type(4)));
typedef bf16_t bf16x8 __attribute__((ext_vector_type(8)));
typedef float f32x4 __attribute__((ext_vector_type(4)));

// One GEMM stage: X' = Xin @ W^T + bias (64x256 @ 256x256^T).
// 16 waves; wave w owns cols w*16..+15, rows 0..63 (4 MFMA row-tiles).
// Per-thread W slice (16 x f32x4) loaded in ONE burst before the MFMA loop
// (single latency exposure; 16 waves of TLP hide the L2 stream).
template <bool FINAL>
__device__ __forceinline__ void gemm_stage(
    const bf16_t* gin, const float* __restrict__ W,
    const float* __restrict__ bias, bf16_t* gout,
    float* __restrict__ ob, int w, int lane) {
  const int lrow = lane & 15, lgrp = lane >> 4;
  const int col = w * 16 + lrow;

  // burst-load this thread's W row-slice (fp32, 128B)
  f32x4 wreg[16];
#pragma unroll
  for (int kk = 0; kk < 8; ++kk) {
    wreg[2 * kk]     = *(const f32x4*)&W[col * DIM + kk * 32 + lgrp * 8];
    wreg[2 * kk + 1] = *(const f32x4*)&W[col * DIM + kk * 32 + lgrp * 8 + 4];
  }
  const float bcv = bias[col];

  f32x4 acc[4];
#pragma unroll
  for (int rt = 0; rt < 4; ++rt) acc[rt] = (f32x4){0.f, 0.f, 0.f, 0.f};

#pragma unroll
  for (int kk = 0; kk < 8; ++kk) {
    const f32x4 w0 = wreg[2 * kk], w1 = wreg[2 * kk + 1];
    bf16x8 bfrag;
    bfrag[0] = (bf16_t)w0[0]; bfrag[1] = (bf16_t)w0[1];
    bfrag[2] = (bf16_t)w0[2]; bfrag[3] = (bf16_t)w0[3];
    bfrag[4] = (bf16_t)w1[0]; bfrag[5] = (bf16_t)w1[1];
    bfrag[6] = (bf16_t)w1[2]; bfrag[7] = (bf16_t)w1[3];
    const int k0 = kk * 32 + lgrp * 8;
#pragma unroll
    for (int rt = 0; rt < 4; ++rt) {
      const int arow = rt * 16 + lrow;
      const bf16x8 afrag =
          *(const bf16x8*)&gin[arow * DIM + (k0 ^ ((arow & 7) << 3))];
      acc[rt] = __builtin_amdgcn_mfma_f32_16x16x32_bf16(afrag, bfrag, acc[rt], 0, 0, 0);
    }
  }

  // epilogue: C/D layout col=lane&15, row=(lane>>4)*4+reg  [m89-verified]
#pragma unroll
  for (int rt = 0; rt < 4; ++rt) {
#pragma unroll
    for (int r = 0; r < 4; ++r) {
      const int row = rt * 16 + lgrp * 4 + r;
      const float val = acc[rt][r] + bcv;
      if (FINAL) {
        ob[row * DIM + col] = val > 0.f ? val : 0.f;
      } else {
        gout[row * DIM + (col ^ ((row & 7) << 3))] = (bf16_t)val;
      }
    }
  }
}

// Single kernel, no workspace, no sync. Block b (256 x 1024):
//   phase 0: read h[b] once (f32x4), col sums, gA = mix(h) (bf16, swizzled)
//   stage 1: gB = gA @ Wa^T + ba
//   stage 2: gA = gB @ Ws^T + bs
//   stage 3: out[b] = relu(gA @ Wh^T + bh)
__global__ __launch_bounds__(1024) void mac3_kernel(
    const float* __restrict__ h,
    const float* __restrict__ Wa, const float* __restrict__ ba,
    const float* __restrict__ Ws, const float* __restrict__ bs,
    const float* __restrict__ Wh, const float* __restrict__ bh,
    float* __restrict__ out) {
  const int b = blockIdx.x;
  const int t = threadIdx.x;
  const int cg = t & 63;   // cols cg*4..+3
  const int rg = t >> 6;   // wave id 0..15; h rows rg*4..+3

  __shared__ __align__(16) bf16_t gA[NAGENT * DIM];  // 32 KB
  __shared__ __align__(16) bf16_t gB[NAGENT * DIM];  // 32 KB (ps overlaid)
  __shared__ float t1pad[DIM];                       // 1 KB (keeps gB clear)

  f32x4* ps = (f32x4*)gB;  // [16][64] col-sum partials, used only in phase 0
  (void)t1pad;

  const float* hb = h + (size_t)b * NAGENT * DIM;

  // ---- phase 0: single-pass h, column sums, g build ----
  f32x4 v[4];
#pragma unroll
  for (int i = 0; i < 4; ++i)
    v[i] = *(const f32x4*)&hb[(rg * 4 + i) * DIM + cg * 4];

  f32x4 s4 = v[0];
#pragma unroll
  for (int i = 1; i < 4; ++i) s4 += v[i];
  ps[rg * 64 + cg] = s4;
  __syncthreads();
  f32x4 hs = ps[0 * 64 + cg];
#pragma unroll
  for (int r = 1; r < 16; ++r) hs += ps[r * 64 + cg];

  const float inv = 1.0f / 63.0f;
#pragma unroll
  for (int i = 0; i < 4; ++i) {
    const int row = rg * 4 + i;
    const f32x4 gv = (hs - v[i]) * inv;
    bf16x4 gb;
    gb[0] = (bf16_t)gv[0]; gb[1] = (bf16_t)gv[1];
    gb[2] = (bf16_t)gv[2]; gb[3] = (bf16_t)gv[3];
    *(bf16x4*)&gA[row * DIM + ((cg * 4) ^ ((row & 7) << 3))] = gb;
  }
  __syncthreads();  // gA ready; ps dead (all hs reads done above)

  // ---- three chained GEMM stages ----
  const int lane = t & 63;
  float* ob = out + (size_t)b * NAGENT * DIM;

  gemm_stage<false>(gA, Wa, ba, gB, nullptr, rg, lane);
  __syncthreads();
  gemm_stage<false>(gB, Ws, bs, gA, nullptr, rg, lane);
  __syncthreads();
  gemm_stage<true>(gA, Wh, bh, nullptr, ob, rg, lane);
}

extern "C" void kernel_launch(void* const* d_in, const int* in_sizes, int n_in,
                              void* d_out, int out_size, void* d_ws, size_t ws_size,
                              hipStream_t stream) {
  const float* h  = (const float*)d_in[0];  // hidden_state (16384,256)
  const float* Wa = (const float*)d_in[1];  // W_act (256,256)
  const float* ba = (const float*)d_in[2];  // b_act (256,)
  const float* Ws = (const float*)d_in[3];  // W_sum (256,256)
  const float* bs = (const float*)d_in[4];  // b_sum (256,)
  const float* Wh = (const float*)d_in[5];  // W_head (256,256)
  const float* bh = (const float*)d_in[6];  // b_head (256,)
  float* out = (float*)d_out;

  mac3_kernel<<<NBATCH, 1024, 0, stream>>>(h, Wa, ba, Ws, bs, Wh, bh, out);
}

// Round 15
// 24.457 us; speedup vs baseline: 4.0068x; 1.3772x over previous
//
#include <hip/hip_runtime.h>
#include <hip/hip_bf16.h>

#define DIM 256
#define NAGENT 64
#define NBATCH 256

typedef __bf16 bf16_t;
typedef bf16_t bf16x4 __attribute__((ext_vector_type(4)));
typedef bf16_t bf16x8 __attribute__((ext_vector_type(8)));
typedef float f32x4 __attribute__((ext_vector_type(4)));

// Prep: block b emits row b of Wsa = bf16(Ws @ Wa), row b of Whbf = bf16(Wh),
// and v[b] = dot(Ws[b],ba) + bs[b].  (re-associated: only ONE 256-wide product)
// 256 blocks x 1024 threads (16 waves, proven TLP config). Per-CU ingest:
// full Wa (256 KB) + 2 rows = half of the old two-stage prep.
__global__ __launch_bounds__(1024) void prep_kernel(
    const float* __restrict__ Ws, const float* __restrict__ Wa,
    const float* __restrict__ Wh, const float* __restrict__ ba,
    const float* __restrict__ bs,
    bf16_t* __restrict__ Wsa, bf16_t* __restrict__ Whbf,
    float* __restrict__ vvec) {
  const int b = blockIdx.x;
  const int t = threadIdx.x;
  const int jg = t & 63;     // output cols jg*4..+3
  const int kc = t >> 6;     // k-chunk 0..15 (16 k's each)

  __shared__ float wsl[DIM];      // Ws row b
  __shared__ f32x4 part[16][64];  // 16 KB partials

  if (t < 64) *(f32x4*)&wsl[t * 4] = *(const f32x4*)&Ws[b * DIM + t * 4];
  __syncthreads();

  // single stage: Wsa row b = wsl @ Wa  (16 independent f32x4 loads/thread)
  {
    f32x4 a = {0.f, 0.f, 0.f, 0.f};
#pragma unroll
    for (int ki = 0; ki < 16; ++ki) {
      const int k = kc * 16 + ki;
      a += wsl[k] * *(const f32x4*)&Wa[k * DIM + jg * 4];
    }
    part[kc][jg] = a;
  }
  // parallel with stage: waves 1 casts Wh row b -> bf16
  if (t >= 64 && t < 128) {
    const int c = t - 64;
    const f32x4 w4 = *(const f32x4*)&Wh[b * DIM + c * 4];
    bf16x4 wb;
    wb[0] = (bf16_t)w4[0]; wb[1] = (bf16_t)w4[1];
    wb[2] = (bf16_t)w4[2]; wb[3] = (bf16_t)w4[3];
    *(bf16x4*)&Whbf[b * DIM + c * 4] = wb;
  }
  __syncthreads();
  if (t < 64) {
    f32x4 s = part[0][t];
#pragma unroll
    for (int r = 1; r < 16; ++r) s += part[r][t];
    bf16x4 wb;
    wb[0] = (bf16_t)s[0]; wb[1] = (bf16_t)s[1];
    wb[2] = (bf16_t)s[2]; wb[3] = (bf16_t)s[3];
    *(bf16x4*)&Wsa[b * DIM + t * 4] = wb;
    // v[b] = dot(wsl, ba) + bs[b]  (wave-local shuffle reduce)
    const f32x4 ws4 = *(const f32x4*)&wsl[t * 4];
    const f32x4 ba4 = *(const f32x4*)&ba[t * 4];
    const f32x4 pp = ws4 * ba4;
    float p = pp[0] + pp[1] + pp[2] + pp[3];
#pragma unroll
    for (int s2 = 32; s2 > 0; s2 >>= 1) p += __shfl_down(p, s2, 64);
    if (t == 0) vvec[b] = p + bs[b];
  }
}

// Fused: block b (512 thr, 8 waves): g = mix(h[b]) -> u = g@Wsa^T + v ->
// out[b] = relu(u@Whbf^T + bh). Both B-operands prefetched into registers
// before their stage's MFMA (stage-2 loads issued before stage-1 compute).
__global__ __launch_bounds__(512) void fused_kernel(
    const float* __restrict__ h, const bf16_t* __restrict__ Wsa,
    const bf16_t* __restrict__ Whbf, const float* __restrict__ vvec,
    const float* __restrict__ bh, float* __restrict__ out) {
  const int b = blockIdx.x;
  const int t = threadIdx.x;
  const int cg = t & 63;   // cols cg*4 .. +3
  const int rg = t >> 6;   // wave id; h rows rg*8 .. +7

  __shared__ __align__(16) bf16_t gA[NAGENT * DIM];  // 32 KB (g, then reused)
  __shared__ __align__(16) bf16_t gB[NAGENT * DIM];  // 32 KB (ps overlay; u)
  f32x4* ps = (f32x4*)gB;  // [8][64] col-sum partials (dead before u written)

  const float* hb = h + (size_t)b * NAGENT * DIM;

  // ---- issue h loads ----
  f32x4 v[8];
#pragma unroll
  for (int i = 0; i < 8; ++i)
    v[i] = *(const f32x4*)&hb[(rg * 8 + i) * DIM + cg * 4];

  // ---- prefetch stage-1 B-fragments (Wsa, wave rg -> cols rg*32..+31) ----
  const int lane = t & 63, lrow = lane & 15, lgrp = lane >> 4;
  bf16x8 bf1[8][2];
#pragma unroll
  for (int kk = 0; kk < 8; ++kk)
#pragma unroll
    for (int ct = 0; ct < 2; ++ct)
      bf1[kk][ct] = *(const bf16x8*)&Wsa[(rg * 32 + ct * 16 + lrow) * DIM +
                                         kk * 32 + lgrp * 8];
  const float vv0 = vvec[rg * 32 + lrow];
  const float vv1 = vvec[rg * 32 + 16 + lrow];
  const float bh0 = bh[rg * 32 + lrow];
  const float bh1 = bh[rg * 32 + 16 + lrow];

  // ---- column sums + g build ----
  f32x4 s4 = v[0];
#pragma unroll
  for (int i = 1; i < 8; ++i) s4 += v[i];
  ps[rg * 64 + cg] = s4;
  __syncthreads();
  f32x4 hs = ps[0 * 64 + cg];
#pragma unroll
  for (int r = 1; r < 8; ++r) hs += ps[r * 64 + cg];

  const float inv = 1.0f / 63.0f;
#pragma unroll
  for (int i = 0; i < 8; ++i) {
    const int row = rg * 8 + i;
    const f32x4 gv = (hs - v[i]) * inv;
    bf16x4 gb;
    gb[0] = (bf16_t)gv[0]; gb[1] = (bf16_t)gv[1];
    gb[2] = (bf16_t)gv[2]; gb[3] = (bf16_t)gv[3];
    *(bf16x4*)&gA[row * DIM + ((cg * 4) ^ ((row & 7) << 3))] = gb;
  }
  __syncthreads();  // gA ready; ps dead

  // ---- issue stage-2 B loads now (hide under stage-1 MFMA) ----
  bf16x8 bf2[8][2];
#pragma unroll
  for (int kk = 0; kk < 8; ++kk)
#pragma unroll
    for (int ct = 0; ct < 2; ++ct)
      bf2[kk][ct] = *(const bf16x8*)&Whbf[(rg * 32 + ct * 16 + lrow) * DIM +
                                          kk * 32 + lgrp * 8];

  // ---- stage 1: u = g @ Wsa^T + v  -> gB (bf16, swizzled) ----
  f32x4 acc[4][2];
#pragma unroll
  for (int rt = 0; rt < 4; ++rt)
#pragma unroll
    for (int ct = 0; ct < 2; ++ct) acc[rt][ct] = (f32x4){0.f, 0.f, 0.f, 0.f};

#pragma unroll
  for (int kk = 0; kk < 8; ++kk) {
    const int k0 = kk * 32 + lgrp * 8;
#pragma unroll
    for (int rt = 0; rt < 4; ++rt) {
      const int arow = rt * 16 + lrow;
      const bf16x8 afrag =
          *(const bf16x8*)&gA[arow * DIM + (k0 ^ ((arow & 7) << 3))];
      acc[rt][0] = __builtin_amdgcn_mfma_f32_16x16x32_bf16(afrag, bf1[kk][0], acc[rt][0], 0, 0, 0);
      acc[rt][1] = __builtin_amdgcn_mfma_f32_16x16x32_bf16(afrag, bf1[kk][1], acc[rt][1], 0, 0, 0);
    }
  }

  // epilogue 1: C/D layout col=lane&15, row=(lane>>4)*4+reg [m89-verified]
#pragma unroll
  for (int ct = 0; ct < 2; ++ct) {
    const int col = rg * 32 + ct * 16 + lrow;
    const float vb = ct ? vv1 : vv0;
#pragma unroll
    for (int rt = 0; rt < 4; ++rt)
#pragma unroll
      for (int r = 0; r < 4; ++r) {
        const int row = rt * 16 + lgrp * 4 + r;
        gB[row * DIM + (col ^ ((row & 7) << 3))] = (bf16_t)(acc[rt][ct][r] + vb);
      }
  }
  __syncthreads();

  // ---- stage 2: out = relu(u @ Whbf^T + bh) ----
#pragma unroll
  for (int rt = 0; rt < 4; ++rt)
#pragma unroll
    for (int ct = 0; ct < 2; ++ct) acc[rt][ct] = (f32x4){0.f, 0.f, 0.f, 0.f};

#pragma unroll
  for (int kk = 0; kk < 8; ++kk) {
    const int k0 = kk * 32 + lgrp * 8;
#pragma unroll
    for (int rt = 0; rt < 4; ++rt) {
      const int arow = rt * 16 + lrow;
      const bf16x8 afrag =
          *(const bf16x8*)&gB[arow * DIM + (k0 ^ ((arow & 7) << 3))];
      acc[rt][0] = __builtin_amdgcn_mfma_f32_16x16x32_bf16(afrag, bf2[kk][0], acc[rt][0], 0, 0, 0);
      acc[rt][1] = __builtin_amdgcn_mfma_f32_16x16x32_bf16(afrag, bf2[kk][1], acc[rt][1], 0, 0, 0);
    }
  }

  float* ob = out + (size_t)b * NAGENT * DIM;
#pragma unroll
  for (int ct = 0; ct < 2; ++ct) {
    const int col = rg * 32 + ct * 16 + lrow;
    const float bb = ct ? bh1 : bh0;
#pragma unroll
    for (int rt = 0; rt < 4; ++rt)
#pragma unroll
      for (int r = 0; r < 4; ++r) {
        const int row = rt * 16 + lgrp * 4 + r;
        const float val = acc[rt][ct][r] + bb;
        ob[row * DIM + col] = val > 0.f ? val : 0.f;
      }
  }
}

extern "C" void kernel_launch(void* const* d_in, const int* in_sizes, int n_in,
                              void* d_out, int out_size, void* d_ws, size_t ws_size,
                              hipStream_t stream) {
  const float* h  = (const float*)d_in[0];  // hidden_state (16384,256)
  const float* Wa = (const float*)d_in[1];  // W_act (256,256)
  const float* ba = (const float*)d_in[2];  // b_act (256,)
  const float* Ws = (const float*)d_in[3];  // W_sum (256,256)
  const float* bs = (const float*)d_in[4];  // b_sum (256,)
  const float* Wh = (const float*)d_in[5];  // W_head (256,256)
  const float* bh = (const float*)d_in[6];  // b_head (256,)
  float* out = (float*)d_out;

  char* ws = (char*)d_ws;
  bf16_t* Wsa  = (bf16_t*)ws;                  // 128 KB: bf16(Ws@Wa)
  bf16_t* Whbf = (bf16_t*)(ws + 128 * 1024);   // 128 KB: bf16(Wh)
  float*  vvec = (float*)(ws + 256 * 1024);    // 1 KB : Ws@ba + bs

  prep_kernel<<<NBATCH, 1024, 0, stream>>>(Ws, Wa, Wh, ba, bs, Wsa, Whbf, vvec);
  fused_kernel<<<NBATCH, 512, 0, stream>>>(h, Wsa, Whbf, vvec, bh, out);
}

// Round 16
// 22.879 us; speedup vs baseline: 4.2832x; 1.0690x over previous
//
#include <hip/hip_runtime.h>
#include <hip/hip_bf16.h>

#define DIM 256
#define NAGENT 64
#define NBATCH 256

typedef __bf16 bf16_t;
typedef bf16_t bf16x4 __attribute__((ext_vector_type(4)));
typedef bf16_t bf16x8 __attribute__((ext_vector_type(8)));
typedef float f32x4 __attribute__((ext_vector_type(4)));

// Prep (verbatim R12, measured-best): block b -> row b of Wc = bf16(Wh@Ws@Wa),
// bc[b]. 256 blocks x 1024 threads; Wa chunk prefetched into registers during
// stage 1 so both 256 KB weight streams are in flight concurrently.
__global__ __launch_bounds__(1024) void prep_kernel(
    const float* __restrict__ Wh, const float* __restrict__ Ws,
    const float* __restrict__ Wa, const float* __restrict__ ba,
    const float* __restrict__ bs, const float* __restrict__ bh,
    bf16_t* __restrict__ Wc, float* __restrict__ bcw) {
  const int b = blockIdx.x;
  const int t = threadIdx.x;
  const int jg = t & 63;     // output cols jg*4..+3
  const int kc = t >> 6;     // k-chunk 0..15 (16 k's each)

  __shared__ float whl[DIM];      // Wh row b
  __shared__ float t1l[DIM];      // Whs row b
  __shared__ f32x4 part[16][64];  // 16 KB partials

  if (t < 64) *(f32x4*)&whl[t * 4] = *(const f32x4*)&Wh[b * DIM + t * 4];

  // prefetch this thread's Wa chunk (independent of whl/t1) — overlaps stage 1
  f32x4 wa[16];
#pragma unroll
  for (int ki = 0; ki < 16; ++ki)
    wa[ki] = *(const f32x4*)&Wa[(kc * 16 + ki) * DIM + jg * 4];

  __syncthreads();  // whl ready

  // ---- stage 1: t1 = whl @ Ws (16 independent f32x4 loads) ----
  {
    f32x4 a = {0.f, 0.f, 0.f, 0.f};
#pragma unroll
    for (int ki = 0; ki < 16; ++ki) {
      const int k = kc * 16 + ki;
      a += whl[k] * *(const f32x4*)&Ws[k * DIM + jg * 4];
    }
    part[kc][jg] = a;
  }
  __syncthreads();
  if (t < 64) {
    f32x4 s = part[0][t];
#pragma unroll
    for (int r = 1; r < 16; ++r) s += part[r][t];
    *(f32x4*)&t1l[t * 4] = s;
  }
  __syncthreads();

  // ---- stage 2: Wc row = t1 @ Wa — pure VALU on prefetched regs ----
  {
    f32x4 a = {0.f, 0.f, 0.f, 0.f};
#pragma unroll
    for (int ki = 0; ki < 16; ++ki) a += t1l[kc * 16 + ki] * wa[ki];
    part[kc][jg] = a;
  }
  __syncthreads();
  if (t < 64) {
    f32x4 s = part[0][t];
#pragma unroll
    for (int r = 1; r < 16; ++r) s += part[r][t];
    bf16x4 wb;
    wb[0] = (bf16_t)s[0]; wb[1] = (bf16_t)s[1];
    wb[2] = (bf16_t)s[2]; wb[3] = (bf16_t)s[3];
    *(bf16x4*)&Wc[b * DIM + t * 4] = wb;
    // bc[b] = dot(t1,ba) + dot(Wh[b],bs) + bh[b]  (wave-local reduce)
    const f32x4 t14 = *(const f32x4*)&t1l[t * 4];
    const f32x4 ba4 = *(const f32x4*)&ba[t * 4];
    const f32x4 wh4 = *(const f32x4*)&whl[t * 4];
    const f32x4 bs4 = *(const f32x4*)&bs[t * 4];
    const f32x4 pp = t14 * ba4 + wh4 * bs4;
    float p = pp[0] + pp[1] + pp[2] + pp[3];
#pragma unroll
    for (int s2 = 32; s2 > 0; s2 >>= 1) p += __shfl_down(p, s2, 64);
    if (t == 0) bcw[b] = p + bh[b];
  }
}

// Fused main (R12 base). CHANGE: MFMA operands swapped (A=Wc frag, B=g frag)
// so D-row = output dim d, D-col = agent (m89: D-row<->A-row, D-col<->B-row).
// Each lane then holds 4 consecutive d per accumulator -> f32x4 stores.
__global__ __launch_bounds__(512) void fused_kernel(
    const float* __restrict__ h, const bf16_t* __restrict__ Wc,
    const float* __restrict__ bcw, float* __restrict__ out) {
  const int b = blockIdx.x;
  const int t = threadIdx.x;
  const int cg = t & 63;   // cols cg*4 .. +3
  const int rg = t >> 6;   // wave id; h rows rg*8 .. +7

  __shared__ __align__(16) bf16_t g[NAGENT * DIM];  // 32 KB, XOR-swizzled
  __shared__ f32x4 ps[8][64];                       // 8 KB

  const float* hb = h + (size_t)b * NAGENT * DIM;

  // issue h loads
  f32x4 v[8];
#pragma unroll
  for (int i = 0; i < 8; ++i)
    v[i] = *(const f32x4*)&hb[(rg * 8 + i) * DIM + cg * 4];

  // prefetch A-fragments: wave rg owns output dims d = rg*32..+31
  const int lane = t & 63, lrow = lane & 15, lgrp = lane >> 4;
  bf16x8 wfrag[8][2];
#pragma unroll
  for (int kk = 0; kk < 8; ++kk) {
#pragma unroll
    for (int dt = 0; dt < 2; ++dt) {
      const int d = rg * 32 + dt * 16 + lrow;
      wfrag[kk][dt] = *(const bf16x8*)&Wc[d * DIM + kk * 32 + lgrp * 8];
    }
  }
  // bias: 4 consecutive d per lane per dt-tile
  f32x4 bcv4[2];
#pragma unroll
  for (int dt = 0; dt < 2; ++dt)
    bcv4[dt] = *(const f32x4*)&bcw[rg * 32 + dt * 16 + lgrp * 4];

  // column sums
  f32x4 s4 = v[0];
#pragma unroll
  for (int i = 1; i < 8; ++i) s4 += v[i];
  ps[rg][cg] = s4;
  __syncthreads();
  f32x4 hs = ps[0][cg];
#pragma unroll
  for (int r = 1; r < 8; ++r) hs += ps[r][cg];

  // g build (bf16, XOR-swizzled)
  const float inv = 1.0f / 63.0f;
#pragma unroll
  for (int i = 0; i < 8; ++i) {
    const int row = rg * 8 + i;
    const f32x4 gv = (hs - v[i]) * inv;
    bf16x4 gb;
    gb[0] = (bf16_t)gv[0]; gb[1] = (bf16_t)gv[1];
    gb[2] = (bf16_t)gv[2]; gb[3] = (bf16_t)gv[3];
    *(bf16x4*)&g[row * DIM + ((cg * 4) ^ ((row & 7) << 3))] = gb;
  }
  __syncthreads();

  // GEMM: acc[dt][at]: D-rows d = rg*32+dt*16.., D-cols agents at*16..
  f32x4 acc[2][4];
#pragma unroll
  for (int dt = 0; dt < 2; ++dt)
#pragma unroll
    for (int at = 0; at < 4; ++at) acc[dt][at] = (f32x4){0.f, 0.f, 0.f, 0.f};

#pragma unroll
  for (int kk = 0; kk < 8; ++kk) {
    const int k0 = kk * 32 + lgrp * 8;
#pragma unroll
    for (int at = 0; at < 4; ++at) {
      const int arow = at * 16 + lrow;  // agent row of g
      const bf16x8 gfrag =
          *(const bf16x8*)&g[arow * DIM + (k0 ^ ((arow & 7) << 3))];
      acc[0][at] = __builtin_amdgcn_mfma_f32_16x16x32_bf16(wfrag[kk][0], gfrag, acc[0][at], 0, 0, 0);
      acc[1][at] = __builtin_amdgcn_mfma_f32_16x16x32_bf16(wfrag[kk][1], gfrag, acc[1][at], 0, 0, 0);
    }
  }

  // epilogue: lane -> agent = at*16 + (lane&15); d = rg*32+dt*16+lgrp*4+r
  // 4 consecutive d per acc -> f32x4 store. relu componentwise.
  float* ob = out + (size_t)b * NAGENT * DIM;
#pragma unroll
  for (int at = 0; at < 4; ++at) {
    const int agent = at * 16 + lrow;
#pragma unroll
    for (int dt = 0; dt < 2; ++dt) {
      const int dbase = rg * 32 + dt * 16 + lgrp * 4;
      f32x4 val = acc[dt][at] + bcv4[dt];
#pragma unroll
      for (int r = 0; r < 4; ++r) val[r] = val[r] > 0.f ? val[r] : 0.f;
      *(f32x4*)&ob[agent * DIM + dbase] = val;
    }
  }
}

extern "C" void kernel_launch(void* const* d_in, const int* in_sizes, int n_in,
                              void* d_out, int out_size, void* d_ws, size_t ws_size,
                              hipStream_t stream) {
  const float* h  = (const float*)d_in[0];  // hidden_state (16384,256)
  const float* Wa = (const float*)d_in[1];  // W_act (256,256)
  const float* ba = (const float*)d_in[2];  // b_act (256,)
  const float* Ws = (const float*)d_in[3];  // W_sum (256,256)
  const float* bs = (const float*)d_in[4];  // b_sum (256,)
  const float* Wh = (const float*)d_in[5];  // W_head (256,256)
  const float* bh = (const float*)d_in[6];  // b_head (256,)
  float* out = (float*)d_out;

  char* ws = (char*)d_ws;
  bf16_t* Wc  = (bf16_t*)ws;                 // 128 KB
  float*  bcw = (float*)(ws + 128 * 1024);   // 1 KB

  prep_kernel<<<NBATCH, 1024, 0, stream>>>(Wh, Ws, Wa, ba, bs, bh, Wc, bcw);
  fused_kernel<<<NBATCH, 512, 0, stream>>>(h, Wc, bcw, out);
}